// Round 10
// baseline (599.930 us; speedup 1.0000x reference)
//
#include <hip/hip_runtime.h>
#include <cstdint>

#define N_TOK 4096
#define DMODEL 512
#define NHEADS 8
#define HDIM 64

typedef unsigned short u16;
typedef __bf16 bf16x8 __attribute__((ext_vector_type(8)));
typedef float f32x4 __attribute__((ext_vector_type(4)));

union U128 { uint4 u; bf16x8 b; u16 s[8]; };

__device__ __forceinline__ u16 f2bf(float f) {           // RNE
  uint32_t u = __builtin_bit_cast(uint32_t, f);
  u += 0x7FFFu + ((u >> 16) & 1u);
  return (u16)(u >> 16);
}
__device__ __forceinline__ float bf2f(u16 s) {
  uint32_t u = ((uint32_t)s) << 16;
  return __builtin_bit_cast(float, u);
}
__device__ __forceinline__ uint32_t fbit(float f) { return __builtin_bit_cast(uint32_t, f); }

#if __has_builtin(__builtin_amdgcn_exp2f)
#define EXP2(x) __builtin_amdgcn_exp2f(x)
#else
#define EXP2(x) __expf((x) * 0.6931471805599453f)
#endif

// async global->LDS, 16B/lane, dest = wave-uniform base + lane*16
__device__ __forceinline__ void ldg2lds16(const void* g, void* s) {
  __builtin_amdgcn_global_load_lds(
      (const __attribute__((address_space(1))) void*)g,
      (__attribute__((address_space(3))) void*)s, 16, 0, 0);
}

// Manual grid barrier: monotone counter, agent-scope atomics (sanctioned
// cross-XCD mechanism).  Safe because all 512 blocks are co-resident:
// 52 KB LDS -> 3 blocks/CU capacity, 8 waves/block -> <=24 waves/CU,
// VGPR <=128 under (512,4).
__device__ __forceinline__ void gridbar(unsigned int* cnt, unsigned int target) {
  __syncthreads();
  if (threadIdx.x == 0) {
    __threadfence();
    __hip_atomic_fetch_add(cnt, 1u, __ATOMIC_RELEASE, __HIP_MEMORY_SCOPE_AGENT);
    while (__hip_atomic_load(cnt, __ATOMIC_ACQUIRE, __HIP_MEMORY_SCOPE_AGENT) < target)
      __builtin_amdgcn_s_sleep(4);
    __threadfence();
  }
  __syncthreads();
}

// ---------------------------------------------------------------------------
// Single mega-kernel: cvt -> proj(QKV) -> attn -> combine -> gemmo -> ln.
// Plain launch (cooperative launch fails in this harness — r6); 5 manual
// grid barriers replace 5 kernel-launch gaps (~18 us each, r3/r5/r8 data).
// grid 512 x 512.
// ---------------------------------------------------------------------------
__global__ __launch_bounds__(512, 4) void fused_kernel(
    const float* __restrict__ Q, const float* __restrict__ K, const float* __restrict__ V,
    const float* __restrict__ WQ, const float* __restrict__ bQ,
    const float* __restrict__ WK, const float* __restrict__ bK,
    const float* __restrict__ WV, const float* __restrict__ bV,
    const float* __restrict__ WO, const float* __restrict__ bO,
    const float* __restrict__ gamma, const float* __restrict__ beta,
    u16* __restrict__ Qb, u16* __restrict__ Kb, u16* __restrict__ Vb,
    u16* __restrict__ WQb, u16* __restrict__ WKb, u16* __restrict__ WVb,
    u16* __restrict__ WOb,
    u16* __restrict__ Qs, u16* __restrict__ Ks, u16* __restrict__ Vt,
    u16* __restrict__ ctx, u16* __restrict__ Opart, float* __restrict__ tmp,
    float* __restrict__ Lpart, float* __restrict__ out,
    unsigned int* __restrict__ cnt)
{
  __shared__ __align__(16) char smem[53248];   // 52 KB union across phases

  const int tid = threadIdx.x;
  const int bid = blockIdx.x;
  const int w = tid >> 6, lane = tid & 63, quad = lane >> 4, l = lane & 15;
  const f32x4 zero = {0.f, 0.f, 0.f, 0.f};

  // ---------------- Phase 0: fp32 -> bf16 convert (Q,K,V + 4 weights) -------
  {
    const int gtid = bid * 512 + tid;          // 0..262143
#pragma unroll
    for (int a = 0; a < 3; ++a) {
      const float* s = (a == 0) ? Q : (a == 1) ? K : V;
      u16* d = (a == 0) ? Qb : (a == 1) ? Kb : Vb;
#pragma unroll
      for (int rep = 0; rep < 2; ++rep) {
        int i = (gtid + rep * 262144) * 4;
        float4 f = *(const float4*)(s + i);
        ushort4 o4;
        o4.x = f2bf(f.x); o4.y = f2bf(f.y); o4.z = f2bf(f.z); o4.w = f2bf(f.w);
        *(ushort4*)(d + i) = o4;
      }
    }
    if (gtid < 65536) {
      int i = gtid * 4;
#pragma unroll
      for (int a = 0; a < 4; ++a) {
        const float* s = (a == 0) ? WQ : (a == 1) ? WK : (a == 2) ? WV : WO;
        u16* d = (a == 0) ? WQb : (a == 1) ? WKb : (a == 2) ? WVb : WOb;
        float4 f = *(const float4*)(s + i);
        ushort4 o4;
        o4.x = f2bf(f.x); o4.y = f2bf(f.y); o4.z = f2bf(f.z); o4.w = f2bf(f.w);
        *(ushort4*)(d + i) = o4;
      }
    }
  }
  gridbar(cnt, 512);

  // ---------------- Phase 1: QKV projection, 1536 tiles of 64x64, 3/block ---
  {
    bf16x8 (*sA)[8][64] = (bf16x8(*)[8][64])smem;           // dbuf 16 KB
    bf16x8 (*sB)[8][64] = (bf16x8(*)[8][64])(smem + 16384); // dbuf 16 KB
    const int wr = w & 3;        // row group (4 x 16 rows)
    const int ws_ = w >> 2;      // col-pair group (2 x 32 cols)

#pragma unroll
    for (int z = 0; z < 3; ++z) {
      const int m0 = (bid >> 3) * 64, j0 = (bid & 7) * 64;
      const u16* A      = (z == 0) ? Qb : (z == 1) ? Kb : Vb;
      const u16* W      = (z == 0) ? WQb : (z == 1) ? WKb : WVb;
      const float* bias = (z == 0) ? bQ : (z == 1) ? bK : bV;

      f32x4 acc[2];
      acc[0] = zero; acc[1] = zero;

      auto stage = [&](int kt, int buf) {
        const int k0 = kt * 64;
        ldg2lds16(A + (size_t)(m0 + lane) * DMODEL + k0 + w * 8, (char*)&sA[buf][w][0]);
        ldg2lds16(W + (size_t)(j0 + lane) * DMODEL + k0 + w * 8, (char*)&sB[buf][w][0]);
      };

      stage(0, 0);
      __syncthreads();
      for (int kt = 0; kt < 8; ++kt) {
        const int buf = kt & 1;
        if (kt + 1 < 8) stage(kt + 1, buf ^ 1);
#pragma unroll
        for (int c = 0; c < 2; ++c) {
          bf16x8 af = sA[buf][c * 4 + quad][wr * 16 + l];
#pragma unroll
          for (int s = 0; s < 2; ++s) {
            bf16x8 bfb = sB[buf][c * 4 + quad][(ws_ * 2 + s) * 16 + l];
            acc[s] = __builtin_amdgcn_mfma_f32_16x16x32_bf16(af, bfb, acc[s], 0, 0, 0);
          }
        }
        __syncthreads();
      }
#pragma unroll
      for (int s = 0; s < 2; ++s) {
        int j = j0 + (ws_ * 2 + s) * 16 + l;
        float bv = bias[j];
        int n0 = m0 + wr * 16 + quad * 4;
        if (z < 2) {
          u16* Y = (z == 0) ? Qs : Ks;
#pragma unroll
          for (int r = 0; r < 4; ++r)
            Y[(size_t)(n0 + r) * DMODEL + j] = f2bf(acc[s][r] + bv);
        } else {
          ushort4 pk;
          pk.x = f2bf(acc[s][0] + bv); pk.y = f2bf(acc[s][1] + bv);
          pk.z = f2bf(acc[s][2] + bv); pk.w = f2bf(acc[s][3] + bv);
          *(ushort4*)(Vt + (size_t)j * N_TOK + n0) = pk;   // V^T write
        }
      }
      __syncthreads();
    }
  }
  gridbar(cnt, 1024);

  // ---------------- Phase 2: flash attention (r8 structure, split-K x4) -----
  // h = bid&7 -> all blocks of head h share an XCD (r5: FETCH 34.8->6.2 MB)
  {
    const int h = bid & 7, split = (bid >> 3) & 3, qt = bid >> 5;
    bf16x8 (*kch)[8][64] = (bf16x8(*)[8][64])smem;             // [buf][chunk][key] 16 KB
    bf16x8 (*vch)[8][64] = (bf16x8(*)[8][64])(smem + 16384);   // 16 KB
    u16 (*pbuf)[32][40] = (u16(*)[32][40])(smem + 32768);      // 20 KB

    const int wq0 = qt * 256 + w * 32;

    bf16x8 qf[2][2];
#pragma unroll
    for (int c = 0; c < 2; ++c)
#pragma unroll
      for (int m = 0; m < 2; ++m) {
        U128 u;
        u.u = *(const uint4*)(Qs + (size_t)(wq0 + m * 16 + l) * DMODEL + h * HDIM + c * 32 + quad * 8);
#pragma unroll
        for (int j = 0; j < 8; ++j) u.s[j] = f2bf(bf2f(u.s[j]) * 0.18033688f);
        qf[c][m] = u.b;
      }

    f32x4 o[2][4];
    float lsum[2] = {0.f, 0.f};
#pragma unroll
    for (int m = 0; m < 2; ++m)
#pragma unroll
      for (int s = 0; s < 4; ++s) o[m][s] = zero;

    auto stage = [&](int it, int buf) {
      const int j0 = split * 1024 + it * 64;
      if (w < 4) {
        const u16* kg = Ks + (size_t)(j0 + lane) * DMODEL + h * HDIM + w * 16;
        ldg2lds16(kg,     (char*)&kch[buf][2 * w][0]);
        ldg2lds16(kg + 8, (char*)&kch[buf][2 * w + 1][0]);
      } else {
        const int w2 = w - 4;
        const u16* vg = Vt + (size_t)(h * HDIM + lane) * N_TOK + j0 + w2 * 16;
        ldg2lds16(vg,     (char*)&vch[buf][2 * w2][0]);
        ldg2lds16(vg + 8, (char*)&vch[buf][2 * w2 + 1][0]);
      }
    };

    stage(0, 0);
    __syncthreads();

    for (int it = 0; it < 16; ++it) {
      const int buf = it & 1;
      if (it + 1 < 16) stage(it + 1, buf ^ 1);   // prefetch overlaps compute

#pragma unroll
      for (int kh = 0; kh < 2; ++kh) {           // two 32-key halves
#pragma unroll
        for (int tt = 0; tt < 2; ++tt) {
          const int t = kh * 2 + tt;
          f32x4 sacc[2];
          sacc[0] = zero; sacc[1] = zero;
#pragma unroll
          for (int c = 0; c < 2; ++c) {
            bf16x8 kf = kch[buf][c * 4 + quad][t * 16 + l];
            sacc[0] = __builtin_amdgcn_mfma_f32_16x16x32_bf16(kf, qf[c][0], sacc[0], 0, 0, 0);
            sacc[1] = __builtin_amdgcn_mfma_f32_16x16x32_bf16(kf, qf[c][1], sacc[1], 0, 0, 0);
          }
#pragma unroll
          for (int m = 0; m < 2; ++m) {
            float p0 = EXP2(sacc[m][0]);
            float p1 = EXP2(sacc[m][1]);
            float p2 = EXP2(sacc[m][2]);
            float p3 = EXP2(sacc[m][3]);
            lsum[m] += (p0 + p1) + (p2 + p3);
            uint2 st;
            st.x = (fbit(p0) >> 16) | (fbit(p1) & 0xFFFF0000u);
            st.y = (fbit(p2) >> 16) | (fbit(p3) & 0xFFFF0000u);
            *(uint2*)&pbuf[w][m * 16 + l][tt * 16 + quad * 4] = st;  // per-wave
          }
        }
        // PV for this key half
        U128 pf0, pf1;
        pf0.u = *(const uint4*)&pbuf[w][l][quad * 8];
        pf1.u = *(const uint4*)&pbuf[w][16 + l][quad * 8];
#pragma unroll
        for (int s = 0; s < 4; ++s) {
          bf16x8 vf = vch[buf][kh * 4 + quad][s * 16 + l];
          o[0][s] = __builtin_amdgcn_mfma_f32_16x16x32_bf16(pf0.b, vf, o[0][s], 0, 0, 0);
          o[1][s] = __builtin_amdgcn_mfma_f32_16x16x32_bf16(pf1.b, vf, o[1][s], 0, 0, 0);
        }
      }
      __syncthreads();
    }

#pragma unroll
    for (int m = 0; m < 2; ++m) {
      lsum[m] += __shfl_xor(lsum[m], 16);
      lsum[m] += __shfl_xor(lsum[m], 32);
    }
    if (quad == 0) {
      Lpart[((size_t)split * NHEADS + h) * N_TOK + wq0 + l]      = lsum[0];
      Lpart[((size_t)split * NHEADS + h) * N_TOK + wq0 + 16 + l] = lsum[1];
    }
    u16* Ob = Opart + ((size_t)(split * NHEADS + h) * N_TOK + wq0) * 64;
#pragma unroll
    for (int m = 0; m < 2; ++m)
#pragma unroll
      for (int s = 0; s < 4; ++s)
#pragma unroll
        for (int r = 0; r < 4; ++r)
          Ob[(size_t)(m * 16 + quad * 4 + r) * 64 + s * 16 + l] = f2bf(o[m][s][r]);
  }
  gridbar(cnt, 1536);

  // ---------------- Phase 3: combine split-K partials -> ctx bf16 -----------
  {
    int idx = bid * 512 + tid;                // exactly 4096*64
    int n = idx >> 6;
    int c8 = idx & 63;
    int h = c8 >> 3;
    int vd0 = (c8 & 7) * 8;

    float acc[8] = {0, 0, 0, 0, 0, 0, 0, 0};
    float lsum = 0.f;
#pragma unroll
    for (int s = 0; s < 4; ++s) {
      U128 u;
      u.u = *(const uint4*)(Opart + ((size_t)(s * NHEADS + h) * N_TOK + n) * 64 + vd0);
#pragma unroll
      for (int j = 0; j < 8; ++j) acc[j] += bf2f(u.s[j]);
      lsum += Lpart[((size_t)s * NHEADS + h) * N_TOK + n];
    }
    float inv = 1.f / lsum;
    U128 u;
#pragma unroll
    for (int j = 0; j < 8; ++j) u.s[j] = f2bf(acc[j] * inv);
    *(uint4*)(ctx + (size_t)n * DMODEL + h * HDIM + vd0) = u.u;
  }
  gridbar(cnt, 2048);

  // ---------------- Phase 4: output projection + bias + residual ------------
  // 512 tiles of 64x64 (64 mt x 8 jt), one per block.
  {
    bf16x8 (*sA)[8][64] = (bf16x8(*)[8][64])smem;
    bf16x8 (*sB)[8][64] = (bf16x8(*)[8][64])(smem + 16384);
    const int m0 = (bid >> 3) * 64, j0 = (bid & 7) * 64;
    const int wr = w & 3;
    const int ws_ = w >> 2;

    f32x4 acc[2];
    acc[0] = zero; acc[1] = zero;

    auto stage = [&](int kt, int buf) {
      const int k0 = kt * 64;
      ldg2lds16(ctx + (size_t)(m0 + lane) * DMODEL + k0 + w * 8, (char*)&sA[buf][w][0]);
      ldg2lds16(WOb + (size_t)(j0 + lane) * DMODEL + k0 + w * 8, (char*)&sB[buf][w][0]);
    };

    stage(0, 0);
    __syncthreads();
    for (int kt = 0; kt < 8; ++kt) {
      const int buf = kt & 1;
      if (kt + 1 < 8) stage(kt + 1, buf ^ 1);
#pragma unroll
      for (int c = 0; c < 2; ++c) {
        bf16x8 af = sA[buf][c * 4 + quad][wr * 16 + l];
#pragma unroll
        for (int s = 0; s < 2; ++s) {
          bf16x8 bfb = sB[buf][c * 4 + quad][(ws_ * 2 + s) * 16 + l];
          acc[s] = __builtin_amdgcn_mfma_f32_16x16x32_bf16(af, bfb, acc[s], 0, 0, 0);
        }
      }
      __syncthreads();
    }
#pragma unroll
    for (int s = 0; s < 2; ++s) {
      int j = j0 + (ws_ * 2 + s) * 16 + l;
      float bv = bO[j];
      int n0 = m0 + wr * 16 + quad * 4;
#pragma unroll
      for (int r = 0; r < 4; ++r)
        tmp[(size_t)(n0 + r) * DMODEL + j] = acc[s][r] + bv + Q[(size_t)(n0 + r) * DMODEL + j];
    }
  }
  gridbar(cnt, 2560);

  // ---------------- Phase 5: LayerNorm (8 rows/block, 1 row/wave) -----------
  {
    const int row = bid * 8 + w;
    const float* x = tmp + (size_t)row * DMODEL + lane * 8;
    float4 a = *(const float4*)x;
    float4 b = *(const float4*)(x + 4);

    float s = a.x + a.y + a.z + a.w + b.x + b.y + b.z + b.w;
#pragma unroll
    for (int m = 1; m < 64; m <<= 1) s += __shfl_xor(s, m);
    float mu = s * (1.f / DMODEL);

    float d0 = a.x - mu, d1 = a.y - mu, d2 = a.z - mu, d3 = a.w - mu;
    float d4 = b.x - mu, d5 = b.y - mu, d6 = b.z - mu, d7 = b.w - mu;
    float v = d0*d0 + d1*d1 + d2*d2 + d3*d3 + d4*d4 + d5*d5 + d6*d6 + d7*d7;
#pragma unroll
    for (int m = 1; m < 64; m <<= 1) v += __shfl_xor(v, m);
    float sc = rsqrtf(v * (1.f / DMODEL) + 1e-5f);

    const float* g = gamma + lane * 8;
    const float* be = beta + lane * 8;
    float4 go = *(const float4*)g;
    float4 g1 = *(const float4*)(g + 4);
    float4 bo = *(const float4*)be;
    float4 b1 = *(const float4*)(be + 4);

    float4 y0, y1;
    y0.x = d0 * sc * go.x + bo.x;  y0.y = d1 * sc * go.y + bo.y;
    y0.z = d2 * sc * go.z + bo.z;  y0.w = d3 * sc * go.w + bo.w;
    y1.x = d4 * sc * g1.x + b1.x;  y1.y = d5 * sc * g1.y + b1.y;
    y1.z = d6 * sc * g1.z + b1.z;  y1.w = d7 * sc * g1.w + b1.w;

    float* yp = out + (size_t)row * DMODEL + lane * 8;
    *(float4*)yp = y0;
    *(float4*)(yp + 4) = y1;
  }
}

// ---------------------------------------------------------------------------
extern "C" void kernel_launch(void* const* d_in, const int* in_sizes, int n_in,
                              void* d_out, int out_size, void* d_ws, size_t ws_size,
                              hipStream_t stream)
{
  const float* Q     = (const float*)d_in[0];
  const float* K     = (const float*)d_in[1];
  const float* V     = (const float*)d_in[2];
  const float* WQ    = (const float*)d_in[3];
  const float* bQ    = (const float*)d_in[4];
  const float* WK    = (const float*)d_in[5];
  const float* bK    = (const float*)d_in[6];
  const float* WV    = (const float*)d_in[7];
  const float* bV    = (const float*)d_in[8];
  const float* WO    = (const float*)d_in[9];
  const float* bO    = (const float*)d_in[10];
  const float* gamma = (const float*)d_in[11];
  const float* beta  = (const float*)d_in[12];

  const size_t MB = 1ull << 20;
  char* ws = (char*)d_ws;
  u16* Qb    = (u16*)(ws + 0 * MB);
  u16* Kb    = (u16*)(ws + 4 * MB);
  u16* Vb    = (u16*)(ws + 8 * MB);
  u16* WQb   = (u16*)(ws + 12 * MB);
  u16* WKb   = (u16*)(ws + 12 * MB + 512 * 1024);
  u16* WVb   = (u16*)(ws + 13 * MB);
  u16* WOb   = (u16*)(ws + 13 * MB + 512 * 1024);
  u16* Qs    = (u16*)(ws + 14 * MB);
  u16* Ks    = (u16*)(ws + 18 * MB);
  u16* Vt    = (u16*)(ws + 22 * MB);
  u16* ctxp  = (u16*)(ws + 26 * MB);
  u16* Opart = (u16*)(ws + 30 * MB);     // 16 MB bf16 (dead after phase 3)
  float* tmp = (float*)(ws + 30 * MB);   // 8 MB, overlays Opart (phase 4+)
  float* Lpart = (float*)(ws + 46 * MB); // 0.5 MB
  unsigned int* cnt = (unsigned int*)(ws + 47 * MB);
  float* outp = (float*)d_out;

  hipMemsetAsync(cnt, 0, 128, stream);   // barrier counter (graph-capturable)
  fused_kernel<<<512, 512, 0, stream>>>(
      Q, K, V, WQ, bQ, WK, bK, WV, bV, WO, bO, gamma, beta,
      Qb, Kb, Vb, WQb, WKb, WVb, WOb,
      Qs, Ks, Vt, ctxp, Opart, tmp, Lpart, outp, cnt);
}

// Round 11
// 287.872 us; speedup vs baseline: 2.0840x; 2.0840x over previous
//
#include <hip/hip_runtime.h>
#include <cstdint>

#define N_TOK 4096
#define DMODEL 512
#define NHEADS 8
#define HDIM 64

typedef unsigned short u16;
typedef __bf16 bf16x8 __attribute__((ext_vector_type(8)));
typedef float f32x4 __attribute__((ext_vector_type(4)));

union U128 { uint4 u; bf16x8 b; u16 s[8]; };

__device__ __forceinline__ u16 f2bf(float f) {           // RNE
  uint32_t u = __builtin_bit_cast(uint32_t, f);
  u += 0x7FFFu + ((u >> 16) & 1u);
  return (u16)(u >> 16);
}
__device__ __forceinline__ float bf2f(u16 s) {
  uint32_t u = ((uint32_t)s) << 16;
  return __builtin_bit_cast(float, u);
}
__device__ __forceinline__ uint32_t fbit(float f) { return __builtin_bit_cast(uint32_t, f); }

#if __has_builtin(__builtin_amdgcn_exp2f)
#define EXP2(x) __builtin_amdgcn_exp2f(x)
#else
#define EXP2(x) __expf((x) * 0.6931471805599453f)
#endif

// async global->LDS, 16B/lane, dest = wave-uniform base + lane*16
__device__ __forceinline__ void ldg2lds16(const void* g, void* s) {
  __builtin_amdgcn_global_load_lds(
      (const __attribute__((address_space(1))) void*)g,
      (__attribute__((address_space(3))) void*)s, 16, 0, 0);
}

// ---------------------------------------------------------------------------
// Kernel 0: fp32 -> bf16 pre-convert of Q,K,V,WQ,WK,WV,WO.  7168 x 256.
// (r4 lesson: conversion must live OUTSIDE GEMM K-loops.)
// ---------------------------------------------------------------------------
__global__ __launch_bounds__(256) void cvt7_kernel(
    const float* __restrict__ Q, const float* __restrict__ K, const float* __restrict__ V,
    const float* __restrict__ WQ, const float* __restrict__ WK, const float* __restrict__ WV,
    const float* __restrict__ WO,
    u16* __restrict__ Qb, u16* __restrict__ Kb, u16* __restrict__ Vb,
    u16* __restrict__ WQb, u16* __restrict__ WKb, u16* __restrict__ WVb,
    u16* __restrict__ WOb)
{
  int b = blockIdx.x;
  const float* src; u16* dst; int rel;
  if      (b < 2048) { src = Q;  dst = Qb;  rel = b; }
  else if (b < 4096) { src = K;  dst = Kb;  rel = b - 2048; }
  else if (b < 6144) { src = V;  dst = Vb;  rel = b - 4096; }
  else if (b < 6400) { src = WQ; dst = WQb; rel = b - 6144; }
  else if (b < 6656) { src = WK; dst = WKb; rel = b - 6400; }
  else if (b < 6912) { src = WV; dst = WVb; rel = b - 6656; }
  else               { src = WO; dst = WOb; rel = b - 6912; }
  int i = (rel * 256 + threadIdx.x) * 4;
  float4 f = *(const float4*)(src + i);
  ushort4 o;
  o.x = f2bf(f.x); o.y = f2bf(f.y); o.z = f2bf(f.z); o.w = f2bf(f.w);
  *(ushort4*)(dst + i) = o;
}

// ---------------------------------------------------------------------------
// Kernel 1: fused QKV projection, 128x64 tile, m=2, double-buffered LDS,
// pure global_load_lds staging (bf16 in).  V branch writes V^T (Vt[j][n]).
// grid (32, 8, 3), block 256.
// ---------------------------------------------------------------------------
__global__ __launch_bounds__(256) void proj3_kernel(
    const u16* __restrict__ Qb, const u16* __restrict__ Kb, const u16* __restrict__ Vb,
    const u16* __restrict__ WQb, const u16* __restrict__ WKb, const u16* __restrict__ WVb,
    const float* __restrict__ bQ, const float* __restrict__ bK, const float* __restrict__ bV,
    u16* __restrict__ Qs, u16* __restrict__ Ks, u16* __restrict__ Vt)
{
  const int z = blockIdx.z;
  const u16* A      = (z == 0) ? Qb : (z == 1) ? Kb : Vb;
  const u16* W      = (z == 0) ? WQb : (z == 1) ? WKb : WVb;
  const float* bias = (z == 0) ? bQ : (z == 1) ? bK : bV;

  const int m0 = blockIdx.x * 128;
  const int j0 = blockIdx.y * 64;
  const int tid = threadIdx.x;
  const int w = tid >> 6, lane = tid & 63, quad = lane >> 4, l = lane & 15;

  __shared__ bf16x8 sA[2][8][128];  // 32 KB
  __shared__ bf16x8 sB[2][8][64];   // 16 KB

  const f32x4 zero = {0.f, 0.f, 0.f, 0.f};
  f32x4 acc[2][4];
#pragma unroll
  for (int m = 0; m < 2; ++m)
#pragma unroll
    for (int s = 0; s < 4; ++s) acc[m][s] = zero;

  auto stage = [&](int kt, int buf) {
    const int k0 = kt * 64;
#pragma unroll
    for (int i = 0; i < 4; ++i) {
      const int chunk = 2 * w + (i >> 1), half = (i & 1) * 64;
      const u16* ag = A + (size_t)(m0 + half + lane) * DMODEL + k0 + chunk * 8;
      ldg2lds16(ag, (char*)&sA[buf][chunk][half]);
    }
#pragma unroll
    for (int i = 0; i < 2; ++i) {
      const int chunk = 2 * w + i;
      const u16* bg = W + (size_t)(j0 + lane) * DMODEL + k0 + chunk * 8;
      ldg2lds16(bg, (char*)&sB[buf][chunk][0]);
    }
  };

  stage(0, 0);
  __syncthreads();
  for (int kt = 0; kt < 8; ++kt) {
    const int buf = kt & 1;
    if (kt + 1 < 8) stage(kt + 1, buf ^ 1);
#pragma unroll
    for (int c = 0; c < 2; ++c) {
      bf16x8 af0 = sA[buf][c * 4 + quad][w * 32 + l];
      bf16x8 af1 = sA[buf][c * 4 + quad][w * 32 + 16 + l];
#pragma unroll
      for (int s = 0; s < 4; ++s) {
        bf16x8 bfb = sB[buf][c * 4 + quad][s * 16 + l];
        acc[0][s] = __builtin_amdgcn_mfma_f32_16x16x32_bf16(af0, bfb, acc[0][s], 0, 0, 0);
        acc[1][s] = __builtin_amdgcn_mfma_f32_16x16x32_bf16(af1, bfb, acc[1][s], 0, 0, 0);
      }
    }
    __syncthreads();
  }

#pragma unroll
  for (int m = 0; m < 2; ++m)
#pragma unroll
    for (int s = 0; s < 4; ++s) {
      int j = j0 + s * 16 + l;
      float bv = bias[j];
      int n0 = m0 + w * 32 + m * 16 + quad * 4;
      if (z < 2) {
        u16* Y = (z == 0) ? Qs : Ks;
#pragma unroll
        for (int r = 0; r < 4; ++r)
          Y[(size_t)(n0 + r) * DMODEL + j] = f2bf(acc[m][s][r] + bv);
      } else {
        ushort4 pk;
        pk.x = f2bf(acc[m][s][0] + bv); pk.y = f2bf(acc[m][s][1] + bv);
        pk.z = f2bf(acc[m][s][2] + bv); pk.w = f2bf(acc[m][s][3] + bv);
        *(ushort4*)(Vt + (size_t)j * N_TOK + n0) = pk;   // V^T write
      }
    }
}

// ---------------------------------------------------------------------------
// Kernel 2: flash attention, S^T = K.Q^T, fixed-max softmax, split-K x8,
// m=2 (r8 structure — the proven local optimum: 60 VGPR, no spill),
// double-buffered K/V, key-half pbuf (52 KB LDS -> 3 blocks/CU),
// XCD-locality grid swizzle.  grid (64 = h+8*split, 16 q-tiles), block 512.
// 1024 blocks fill the 3-block/CU LDS capacity (r8's 512 could only use 2).
// ---------------------------------------------------------------------------
__global__ __launch_bounds__(512, 4) void attn_kernel(
    const u16* __restrict__ Qs, const u16* __restrict__ Ks,
    const u16* __restrict__ Vt, u16* __restrict__ Opart, float* __restrict__ Lpart)
{
  const int hs = blockIdx.x;                 // h + 8*split
  const int h = hs & 7, split = hs >> 3;     // split 0..7
  const int qt = blockIdx.y;
  const int tid = threadIdx.x;
  const int w = tid >> 6, lane = tid & 63, quad = lane >> 4, l = lane & 15;

  __shared__ bf16x8 kch[2][8][64];               // 16 KB  [buf][d-chunk][key]
  __shared__ bf16x8 vch[2][8][64];               // 16 KB  [buf][key-chunk][vd]
  __shared__ __align__(16) u16 pbuf[8][32][40];  // 20 KB  [wave][q][key-half]

  const int wq0 = qt * 256 + w * 32;

  // Q fragments (B-operand), pre-scaled by log2(e)/8
  bf16x8 qf[2][2];
#pragma unroll
  for (int c = 0; c < 2; ++c)
#pragma unroll
    for (int m = 0; m < 2; ++m) {
      U128 u;
      u.u = *(const uint4*)(Qs + (size_t)(wq0 + m * 16 + l) * DMODEL + h * HDIM + c * 32 + quad * 8);
#pragma unroll
      for (int j = 0; j < 8; ++j) u.s[j] = f2bf(bf2f(u.s[j]) * 0.18033688f);
      qf[c][m] = u.b;
    }

  const f32x4 zero = {0.f, 0.f, 0.f, 0.f};
  f32x4 o[2][4];
  float lsum[2] = {0.f, 0.f};
#pragma unroll
  for (int m = 0; m < 2; ++m)
#pragma unroll
    for (int s = 0; s < 4; ++s) o[m][s] = zero;

  auto stage = [&](int it, int buf) {
    const int j0 = split * 512 + it * 64;
    if (w < 4) {            // waves 0-3 stage K (8 KB)
      const u16* kg = Ks + (size_t)(j0 + lane) * DMODEL + h * HDIM + w * 16;
      ldg2lds16(kg,     (char*)&kch[buf][2 * w][0]);
      ldg2lds16(kg + 8, (char*)&kch[buf][2 * w + 1][0]);
    } else {                // waves 4-7 stage V^T (8 KB)
      const int w2 = w - 4;
      const u16* vg = Vt + (size_t)(h * HDIM + lane) * N_TOK + j0 + w2 * 16;
      ldg2lds16(vg,     (char*)&vch[buf][2 * w2][0]);
      ldg2lds16(vg + 8, (char*)&vch[buf][2 * w2 + 1][0]);
    }
  };

  stage(0, 0);
  __syncthreads();

  for (int it = 0; it < 8; ++it) {
    const int buf = it & 1;
    if (it + 1 < 8) stage(it + 1, buf ^ 1);    // prefetch overlaps compute

#pragma unroll
    for (int kh = 0; kh < 2; ++kh) {           // two 32-key halves
#pragma unroll
      for (int tt = 0; tt < 2; ++tt) {
        const int t = kh * 2 + tt;
        f32x4 sacc[2];
        sacc[0] = zero; sacc[1] = zero;
#pragma unroll
        for (int c = 0; c < 2; ++c) {
          bf16x8 kf = kch[buf][c * 4 + quad][t * 16 + l];
          sacc[0] = __builtin_amdgcn_mfma_f32_16x16x32_bf16(kf, qf[c][0], sacc[0], 0, 0, 0);
          sacc[1] = __builtin_amdgcn_mfma_f32_16x16x32_bf16(kf, qf[c][1], sacc[1], 0, 0, 0);
        }
#pragma unroll
        for (int m = 0; m < 2; ++m) {
          float p0 = EXP2(sacc[m][0]);
          float p1 = EXP2(sacc[m][1]);
          float p2 = EXP2(sacc[m][2]);
          float p3 = EXP2(sacc[m][3]);
          lsum[m] += (p0 + p1) + (p2 + p3);
          uint2 st;
          st.x = (fbit(p0) >> 16) | (fbit(p1) & 0xFFFF0000u);
          st.y = (fbit(p2) >> 16) | (fbit(p3) & 0xFFFF0000u);
          *(uint2*)&pbuf[w][m * 16 + l][tt * 16 + quad * 4] = st;   // per-wave
        }
      }
      // PV for this key half (contraction = 32 keys, quad covers them)
      U128 pf0, pf1;
      pf0.u = *(const uint4*)&pbuf[w][l][quad * 8];
      pf1.u = *(const uint4*)&pbuf[w][16 + l][quad * 8];
#pragma unroll
      for (int s = 0; s < 4; ++s) {
        bf16x8 vf = vch[buf][kh * 4 + quad][s * 16 + l];
        o[0][s] = __builtin_amdgcn_mfma_f32_16x16x32_bf16(pf0.b, vf, o[0][s], 0, 0, 0);
        o[1][s] = __builtin_amdgcn_mfma_f32_16x16x32_bf16(pf1.b, vf, o[1][s], 0, 0, 0);
      }
    }
    __syncthreads();   // publishes next buf's loads; orders buf reuse
  }

#pragma unroll
  for (int m = 0; m < 2; ++m) {
    lsum[m] += __shfl_xor(lsum[m], 16);
    lsum[m] += __shfl_xor(lsum[m], 32);
  }
  if (quad == 0) {
    Lpart[((size_t)split * NHEADS + h) * N_TOK + wq0 + l]      = lsum[0];
    Lpart[((size_t)split * NHEADS + h) * N_TOK + wq0 + 16 + l] = lsum[1];
  }
  // Opart[split][h][q][vd] bf16 (unnormalized)
  u16* Ob = Opart + ((size_t)(split * NHEADS + h) * N_TOK + wq0) * 64;
#pragma unroll
  for (int m = 0; m < 2; ++m)
#pragma unroll
    for (int s = 0; s < 4; ++s)
#pragma unroll
      for (int r = 0; r < 4; ++r)
        Ob[(size_t)(m * 16 + quad * 4 + r) * 64 + s * 16 + l] = f2bf(o[m][s][r]);
}

// ---------------------------------------------------------------------------
// Kernel 3: combine split-K partials (8 splits) -> ctx bf16.  1024 x 256.
// ---------------------------------------------------------------------------
__global__ __launch_bounds__(256) void combine_kernel(
    const u16* __restrict__ Opart, const float* __restrict__ Lpart,
    u16* __restrict__ ctx)
{
  int idx = blockIdx.x * 256 + threadIdx.x;
  int n = idx >> 6;
  int c8 = idx & 63;
  int h = c8 >> 3;
  int vd0 = (c8 & 7) * 8;

  float acc[8] = {0, 0, 0, 0, 0, 0, 0, 0};
  float lsum = 0.f;
#pragma unroll
  for (int s = 0; s < 8; ++s) {
    U128 u;
    u.u = *(const uint4*)(Opart + ((size_t)(s * NHEADS + h) * N_TOK + n) * 64 + vd0);
#pragma unroll
    for (int j = 0; j < 8; ++j) acc[j] += bf2f(u.s[j]);
    lsum += Lpart[((size_t)s * NHEADS + h) * N_TOK + n];
  }
  float inv = 1.f / lsum;
  U128 u;
#pragma unroll
  for (int j = 0; j < 8; ++j) u.s[j] = f2bf(acc[j] * inv);
  *(uint4*)(ctx + (size_t)n * DMODEL + h * HDIM + vd0) = u.u;
}

// ---------------------------------------------------------------------------
// Kernel 4: output projection + bias + residual, 64x64 tile, double-buffered.
// grid (64, 8) = 512 blocks = 2/CU (r8's 128-tile gave 256 blocks = 1/CU).
// ---------------------------------------------------------------------------
__global__ __launch_bounds__(256) void gemmo_kernel(
    const u16* __restrict__ ctx, const u16* __restrict__ WOb,
    const float* __restrict__ bO, const float* __restrict__ resid,
    float* __restrict__ Y)
{
  const int m0 = blockIdx.x * 64;
  const int j0 = blockIdx.y * 64;
  const int tid = threadIdx.x;
  const int w = tid >> 6, lane = tid & 63, quad = lane >> 4, l = lane & 15;

  __shared__ bf16x8 sA[2][8][64];  // 16 KB
  __shared__ bf16x8 sB[2][8][64];  // 16 KB

  const f32x4 zero = {0.f, 0.f, 0.f, 0.f};
  f32x4 acc[4];
#pragma unroll
  for (int s = 0; s < 4; ++s) acc[s] = zero;

  auto stage = [&](int kt, int buf) {
    const int k0 = kt * 64;
#pragma unroll
    for (int i = 0; i < 2; ++i) {
      const int chunk = 2 * w + i;
      const u16* ag = ctx + (size_t)(m0 + lane) * DMODEL + k0 + chunk * 8;
      ldg2lds16(ag, (char*)&sA[buf][chunk][0]);
      const u16* bg = WOb + (size_t)(j0 + lane) * DMODEL + k0 + chunk * 8;
      ldg2lds16(bg, (char*)&sB[buf][chunk][0]);
    }
  };

  stage(0, 0);
  __syncthreads();
  for (int kt = 0; kt < 8; ++kt) {
    const int buf = kt & 1;
    if (kt + 1 < 8) stage(kt + 1, buf ^ 1);
#pragma unroll
    for (int c = 0; c < 2; ++c) {
      bf16x8 af = sA[buf][c * 4 + quad][w * 16 + l];
#pragma unroll
      for (int s = 0; s < 4; ++s) {
        bf16x8 bfb = sB[buf][c * 4 + quad][s * 16 + l];
        acc[s] = __builtin_amdgcn_mfma_f32_16x16x32_bf16(af, bfb, acc[s], 0, 0, 0);
      }
    }
    __syncthreads();
  }
#pragma unroll
  for (int s = 0; s < 4; ++s) {
    int j = j0 + s * 16 + l;
    float bv = bO[j];
    int n0 = m0 + w * 16 + quad * 4;
#pragma unroll
    for (int r = 0; r < 4; ++r)
      Y[(size_t)(n0 + r) * DMODEL + j] = acc[s][r] + bv + resid[(size_t)(n0 + r) * DMODEL + j];
  }
}

// ---------------------------------------------------------------------------
// Kernel 5: LayerNorm, one wave per row
// ---------------------------------------------------------------------------
__global__ __launch_bounds__(256) void ln_kernel(
    const float* __restrict__ X, const float* __restrict__ gamma,
    const float* __restrict__ beta, float* __restrict__ Y)
{
  const int w = threadIdx.x >> 6, lane = threadIdx.x & 63;
  const int row = blockIdx.x * 4 + w;
  const float* x = X + (size_t)row * DMODEL + lane * 8;
  float4 a = *(const float4*)x;
  float4 b = *(const float4*)(x + 4);

  float s = a.x + a.y + a.z + a.w + b.x + b.y + b.z + b.w;
#pragma unroll
  for (int m = 1; m < 64; m <<= 1) s += __shfl_xor(s, m);
  float mu = s * (1.f / DMODEL);

  float d0 = a.x - mu, d1 = a.y - mu, d2 = a.z - mu, d3 = a.w - mu;
  float d4 = b.x - mu, d5 = b.y - mu, d6 = b.z - mu, d7 = b.w - mu;
  float v = d0*d0 + d1*d1 + d2*d2 + d3*d3 + d4*d4 + d5*d5 + d6*d6 + d7*d7;
#pragma unroll
  for (int m = 1; m < 64; m <<= 1) v += __shfl_xor(v, m);
  float sc = rsqrtf(v * (1.f / DMODEL) + 1e-5f);

  const float* g = gamma + lane * 8;
  const float* be = beta + lane * 8;
  float4 go = *(const float4*)g;
  float4 g1 = *(const float4*)(g + 4);
  float4 bo = *(const float4*)be;
  float4 b1 = *(const float4*)(be + 4);

  float4 y0, y1;
  y0.x = d0 * sc * go.x + bo.x;  y0.y = d1 * sc * go.y + bo.y;
  y0.z = d2 * sc * go.z + bo.z;  y0.w = d3 * sc * go.w + bo.w;
  y1.x = d4 * sc * g1.x + b1.x;  y1.y = d5 * sc * g1.y + b1.y;
  y1.z = d6 * sc * g1.z + b1.z;  y1.w = d7 * sc * g1.w + b1.w;

  float* yp = Y + (size_t)row * DMODEL + lane * 8;
  *(float4*)yp = y0;
  *(float4*)(yp + 4) = y1;
}

// ---------------------------------------------------------------------------
extern "C" void kernel_launch(void* const* d_in, const int* in_sizes, int n_in,
                              void* d_out, int out_size, void* d_ws, size_t ws_size,
                              hipStream_t stream)
{
  const float* Q     = (const float*)d_in[0];
  const float* K     = (const float*)d_in[1];
  const float* V     = (const float*)d_in[2];
  const float* WQ    = (const float*)d_in[3];
  const float* bQ    = (const float*)d_in[4];
  const float* WK    = (const float*)d_in[5];
  const float* bK    = (const float*)d_in[6];
  const float* WV    = (const float*)d_in[7];
  const float* bV    = (const float*)d_in[8];
  const float* WO    = (const float*)d_in[9];
  const float* bO    = (const float*)d_in[10];
  const float* gamma = (const float*)d_in[11];
  const float* beta  = (const float*)d_in[12];

  const size_t MB = 1ull << 20;
  char* ws = (char*)d_ws;
  u16* Qb   = (u16*)(ws + 0 * MB);                  // 4 MB each
  u16* Kb   = (u16*)(ws + 4 * MB);
  u16* Vb   = (u16*)(ws + 8 * MB);
  u16* WQb  = (u16*)(ws + 12 * MB);                 // 0.5 MB each
  u16* WKb  = (u16*)(ws + 12 * MB + 512 * 1024);
  u16* WVb  = (u16*)(ws + 13 * MB);
  u16* WOb  = (u16*)(ws + 13 * MB + 512 * 1024);
  u16* Qs   = (u16*)(ws + 14 * MB);                 // 4 MB each
  u16* Ks   = (u16*)(ws + 18 * MB);
  u16* Vt   = (u16*)(ws + 22 * MB);                 // projected V^T [j][n]
  u16* ctx  = (u16*)(ws + 26 * MB);
  u16* Opart = (u16*)(ws + 30 * MB);                // 32 MB bf16 (8 splits; dead after combine)
  float* tmp = (float*)(ws + 30 * MB);              // 8 MB, overlays Opart
  float* Lpart = (float*)(ws + 62 * MB);            // 1 MB
  float* out = (float*)d_out;

  cvt7_kernel<<<7168, 256, 0, stream>>>(Q, K, V, WQ, WK, WV, WO,
                                        Qb, Kb, Vb, WQb, WKb, WVb, WOb);
  proj3_kernel<<<dim3(32, 8, 3), 256, 0, stream>>>(Qb, Kb, Vb, WQb, WKb, WVb,
                                                   bQ, bK, bV, Qs, Ks, Vt);
  attn_kernel<<<dim3(64, 16), 512, 0, stream>>>(Qs, Ks, Vt, Opart, Lpart);
  combine_kernel<<<1024, 256, 0, stream>>>(Opart, Lpart, ctx);
  gemmo_kernel<<<dim3(64, 8), 256, 0, stream>>>(ctx, WOb, bO, Q, tmp);
  ln_kernel<<<1024, 256, 0, stream>>>(tmp, gamma, beta, out);
}

// Round 12
// 180.646 us; speedup vs baseline: 3.3210x; 1.5936x over previous
//
#include <hip/hip_runtime.h>
#include <cstdint>

#define N_TOK 4096
#define DMODEL 512
#define NHEADS 8
#define HDIM 64

typedef unsigned short u16;
typedef __bf16 bf16x8 __attribute__((ext_vector_type(8)));
typedef float f32x4 __attribute__((ext_vector_type(4)));

union U128 { uint4 u; bf16x8 b; u16 s[8]; };

__device__ __forceinline__ u16 f2bf(float f) {           // RNE
  uint32_t u = __builtin_bit_cast(uint32_t, f);
  u += 0x7FFFu + ((u >> 16) & 1u);
  return (u16)(u >> 16);
}
__device__ __forceinline__ float bf2f(u16 s) {
  uint32_t u = ((uint32_t)s) << 16;
  return __builtin_bit_cast(float, u);
}
__device__ __forceinline__ uint32_t fbit(float f) { return __builtin_bit_cast(uint32_t, f); }

#if __has_builtin(__builtin_amdgcn_exp2f)
#define EXP2(x) __builtin_amdgcn_exp2f(x)
#else
#define EXP2(x) __expf((x) * 0.6931471805599453f)
#endif

// async global->LDS, 16B/lane, dest = wave-uniform base + lane*16
__device__ __forceinline__ void ldg2lds16(const void* g, void* s) {
  __builtin_amdgcn_global_load_lds(
      (const __attribute__((address_space(1))) void*)g,
      (__attribute__((address_space(3))) void*)s, 16, 0, 0);
}

// ---------------------------------------------------------------------------
// Kernel 0: fp32 -> bf16 pre-convert of Q,K,V,WQ,WK,WV,WO.  7168 x 256.
// (r4 lesson: conversion must live OUTSIDE GEMM K-loops.)
// ---------------------------------------------------------------------------
__global__ __launch_bounds__(256) void cvt7_kernel(
    const float* __restrict__ Q, const float* __restrict__ K, const float* __restrict__ V,
    const float* __restrict__ WQ, const float* __restrict__ WK, const float* __restrict__ WV,
    const float* __restrict__ WO,
    u16* __restrict__ Qb, u16* __restrict__ Kb, u16* __restrict__ Vb,
    u16* __restrict__ WQb, u16* __restrict__ WKb, u16* __restrict__ WVb,
    u16* __restrict__ WOb)
{
  int b = blockIdx.x;
  const float* src; u16* dst; int rel;
  if      (b < 2048) { src = Q;  dst = Qb;  rel = b; }
  else if (b < 4096) { src = K;  dst = Kb;  rel = b - 2048; }
  else if (b < 6144) { src = V;  dst = Vb;  rel = b - 4096; }
  else if (b < 6400) { src = WQ; dst = WQb; rel = b - 6144; }
  else if (b < 6656) { src = WK; dst = WKb; rel = b - 6400; }
  else if (b < 6912) { src = WV; dst = WVb; rel = b - 6656; }
  else               { src = WO; dst = WOb; rel = b - 6912; }
  int i = (rel * 256 + threadIdx.x) * 4;
  float4 f = *(const float4*)(src + i);
  ushort4 o;
  o.x = f2bf(f.x); o.y = f2bf(f.y); o.z = f2bf(f.z); o.w = f2bf(f.w);
  *(ushort4*)(dst + i) = o;
}

// ---------------------------------------------------------------------------
// Kernel 1: fused QKV projection, 128x64 tile, m=2, double-buffered LDS,
// pure global_load_lds staging (bf16 in).  V branch writes V^T (Vt[j][n]).
// grid (32, 8, 3), block 256.
// ---------------------------------------------------------------------------
__global__ __launch_bounds__(256) void proj3_kernel(
    const u16* __restrict__ Qb, const u16* __restrict__ Kb, const u16* __restrict__ Vb,
    const u16* __restrict__ WQb, const u16* __restrict__ WKb, const u16* __restrict__ WVb,
    const float* __restrict__ bQ, const float* __restrict__ bK, const float* __restrict__ bV,
    u16* __restrict__ Qs, u16* __restrict__ Ks, u16* __restrict__ Vt)
{
  const int z = blockIdx.z;
  const u16* A      = (z == 0) ? Qb : (z == 1) ? Kb : Vb;
  const u16* W      = (z == 0) ? WQb : (z == 1) ? WKb : WVb;
  const float* bias = (z == 0) ? bQ : (z == 1) ? bK : bV;

  const int m0 = blockIdx.x * 128;
  const int j0 = blockIdx.y * 64;
  const int tid = threadIdx.x;
  const int w = tid >> 6, lane = tid & 63, quad = lane >> 4, l = lane & 15;

  __shared__ bf16x8 sA[2][8][128];  // 32 KB
  __shared__ bf16x8 sB[2][8][64];   // 16 KB

  const f32x4 zero = {0.f, 0.f, 0.f, 0.f};
  f32x4 acc[2][4];
#pragma unroll
  for (int m = 0; m < 2; ++m)
#pragma unroll
    for (int s = 0; s < 4; ++s) acc[m][s] = zero;

  auto stage = [&](int kt, int buf) {
    const int k0 = kt * 64;
#pragma unroll
    for (int i = 0; i < 4; ++i) {
      const int chunk = 2 * w + (i >> 1), half = (i & 1) * 64;
      const u16* ag = A + (size_t)(m0 + half + lane) * DMODEL + k0 + chunk * 8;
      ldg2lds16(ag, (char*)&sA[buf][chunk][half]);
    }
#pragma unroll
    for (int i = 0; i < 2; ++i) {
      const int chunk = 2 * w + i;
      const u16* bg = W + (size_t)(j0 + lane) * DMODEL + k0 + chunk * 8;
      ldg2lds16(bg, (char*)&sB[buf][chunk][0]);
    }
  };

  stage(0, 0);
  __syncthreads();
  for (int kt = 0; kt < 8; ++kt) {
    const int buf = kt & 1;
    if (kt + 1 < 8) stage(kt + 1, buf ^ 1);
#pragma unroll
    for (int c = 0; c < 2; ++c) {
      bf16x8 af0 = sA[buf][c * 4 + quad][w * 32 + l];
      bf16x8 af1 = sA[buf][c * 4 + quad][w * 32 + 16 + l];
#pragma unroll
      for (int s = 0; s < 4; ++s) {
        bf16x8 bfb = sB[buf][c * 4 + quad][s * 16 + l];
        acc[0][s] = __builtin_amdgcn_mfma_f32_16x16x32_bf16(af0, bfb, acc[0][s], 0, 0, 0);
        acc[1][s] = __builtin_amdgcn_mfma_f32_16x16x32_bf16(af1, bfb, acc[1][s], 0, 0, 0);
      }
    }
    __syncthreads();
  }

#pragma unroll
  for (int m = 0; m < 2; ++m)
#pragma unroll
    for (int s = 0; s < 4; ++s) {
      int j = j0 + s * 16 + l;
      float bv = bias[j];
      int n0 = m0 + w * 32 + m * 16 + quad * 4;
      if (z < 2) {
        u16* Y = (z == 0) ? Qs : Ks;
#pragma unroll
        for (int r = 0; r < 4; ++r)
          Y[(size_t)(n0 + r) * DMODEL + j] = f2bf(acc[m][s][r] + bv);
      } else {
        ushort4 pk;
        pk.x = f2bf(acc[m][s][0] + bv); pk.y = f2bf(acc[m][s][1] + bv);
        pk.z = f2bf(acc[m][s][2] + bv); pk.w = f2bf(acc[m][s][3] + bv);
        *(ushort4*)(Vt + (size_t)j * N_TOK + n0) = pk;   // V^T write
      }
    }
}

// ---------------------------------------------------------------------------
// Kernel 2: flash attention (r8 config — the verified local optimum).
// S^T = K.Q^T, fixed-max softmax, split-K x4, double-buffered K/V,
// key-half pbuf (52 KB LDS), XCD-locality swizzle with FULLY CO-RESIDENT
// grid: (32 = h+8*split, 16 q-tiles) = 512 blocks = 2/CU.
// r11 lesson: 1024 blocks break co-residency -> tail blocks land on wrong
// XCDs -> L2 reuse collapses (FETCH 6->163 MB).  Do not exceed 512 blocks.
// r7/r9 lesson: no tighter launch_bounds — spills accumulators to scratch.
// ---------------------------------------------------------------------------
__global__ __launch_bounds__(512, 4) void attn_kernel(
    const u16* __restrict__ Qs, const u16* __restrict__ Ks,
    const u16* __restrict__ Vt, u16* __restrict__ Opart, float* __restrict__ Lpart)
{
  const int hs = blockIdx.x;                 // h + 8*split
  const int h = hs & 7, split = hs >> 3;
  const int qt = blockIdx.y;
  const int tid = threadIdx.x;
  const int w = tid >> 6, lane = tid & 63, quad = lane >> 4, l = lane & 15;

  __shared__ bf16x8 kch[2][8][64];               // 16 KB  [buf][d-chunk][key]
  __shared__ bf16x8 vch[2][8][64];               // 16 KB  [buf][key-chunk][vd]
  __shared__ __align__(16) u16 pbuf[8][32][40];  // 20 KB  [wave][q][key-half]

  const int wq0 = qt * 256 + w * 32;

  // Q fragments (B-operand), pre-scaled by log2(e)/8
  bf16x8 qf[2][2];
#pragma unroll
  for (int c = 0; c < 2; ++c)
#pragma unroll
    for (int m = 0; m < 2; ++m) {
      U128 u;
      u.u = *(const uint4*)(Qs + (size_t)(wq0 + m * 16 + l) * DMODEL + h * HDIM + c * 32 + quad * 8);
#pragma unroll
      for (int j = 0; j < 8; ++j) u.s[j] = f2bf(bf2f(u.s[j]) * 0.18033688f);
      qf[c][m] = u.b;
    }

  const f32x4 zero = {0.f, 0.f, 0.f, 0.f};
  f32x4 o[2][4];
  float lsum[2] = {0.f, 0.f};
#pragma unroll
  for (int m = 0; m < 2; ++m)
#pragma unroll
    for (int s = 0; s < 4; ++s) o[m][s] = zero;

  auto stage = [&](int it, int buf) {
    const int j0 = split * 1024 + it * 64;
    if (w < 4) {            // waves 0-3 stage K (8 KB)
      const u16* kg = Ks + (size_t)(j0 + lane) * DMODEL + h * HDIM + w * 16;
      ldg2lds16(kg,     (char*)&kch[buf][2 * w][0]);
      ldg2lds16(kg + 8, (char*)&kch[buf][2 * w + 1][0]);
    } else {                // waves 4-7 stage V^T (8 KB)
      const int w2 = w - 4;
      const u16* vg = Vt + (size_t)(h * HDIM + lane) * N_TOK + j0 + w2 * 16;
      ldg2lds16(vg,     (char*)&vch[buf][2 * w2][0]);
      ldg2lds16(vg + 8, (char*)&vch[buf][2 * w2 + 1][0]);
    }
  };

  stage(0, 0);
  __syncthreads();

  for (int it = 0; it < 16; ++it) {
    const int buf = it & 1;
    if (it + 1 < 16) stage(it + 1, buf ^ 1);   // prefetch overlaps compute

#pragma unroll
    for (int kh = 0; kh < 2; ++kh) {           // two 32-key halves
#pragma unroll
      for (int tt = 0; tt < 2; ++tt) {
        const int t = kh * 2 + tt;
        f32x4 sacc[2];
        sacc[0] = zero; sacc[1] = zero;
#pragma unroll
        for (int c = 0; c < 2; ++c) {
          bf16x8 kf = kch[buf][c * 4 + quad][t * 16 + l];
          sacc[0] = __builtin_amdgcn_mfma_f32_16x16x32_bf16(kf, qf[c][0], sacc[0], 0, 0, 0);
          sacc[1] = __builtin_amdgcn_mfma_f32_16x16x32_bf16(kf, qf[c][1], sacc[1], 0, 0, 0);
        }
#pragma unroll
        for (int m = 0; m < 2; ++m) {
          float p0 = EXP2(sacc[m][0]);
          float p1 = EXP2(sacc[m][1]);
          float p2 = EXP2(sacc[m][2]);
          float p3 = EXP2(sacc[m][3]);
          lsum[m] += (p0 + p1) + (p2 + p3);
          uint2 st;
          st.x = (fbit(p0) >> 16) | (fbit(p1) & 0xFFFF0000u);
          st.y = (fbit(p2) >> 16) | (fbit(p3) & 0xFFFF0000u);
          *(uint2*)&pbuf[w][m * 16 + l][tt * 16 + quad * 4] = st;   // per-wave
        }
      }
      // PV for this key half (contraction = 32 keys, quad covers them)
      U128 pf0, pf1;
      pf0.u = *(const uint4*)&pbuf[w][l][quad * 8];
      pf1.u = *(const uint4*)&pbuf[w][16 + l][quad * 8];
#pragma unroll
      for (int s = 0; s < 4; ++s) {
        bf16x8 vf = vch[buf][kh * 4 + quad][s * 16 + l];
        o[0][s] = __builtin_amdgcn_mfma_f32_16x16x32_bf16(pf0.b, vf, o[0][s], 0, 0, 0);
        o[1][s] = __builtin_amdgcn_mfma_f32_16x16x32_bf16(pf1.b, vf, o[1][s], 0, 0, 0);
      }
    }
    __syncthreads();   // publishes next buf's loads; orders buf reuse
  }

#pragma unroll
  for (int m = 0; m < 2; ++m) {
    lsum[m] += __shfl_xor(lsum[m], 16);
    lsum[m] += __shfl_xor(lsum[m], 32);
  }
  if (quad == 0) {
    Lpart[((size_t)split * NHEADS + h) * N_TOK + wq0 + l]      = lsum[0];
    Lpart[((size_t)split * NHEADS + h) * N_TOK + wq0 + 16 + l] = lsum[1];
  }
  // Opart[split][h][q][vd] bf16 (unnormalized)
  u16* Ob = Opart + ((size_t)(split * NHEADS + h) * N_TOK + wq0) * 64;
#pragma unroll
  for (int m = 0; m < 2; ++m)
#pragma unroll
    for (int s = 0; s < 4; ++s)
#pragma unroll
      for (int r = 0; r < 4; ++r)
        Ob[(size_t)(m * 16 + quad * 4 + r) * 64 + s * 16 + l] = f2bf(o[m][s][r]);
}

// ---------------------------------------------------------------------------
// Kernel 3: combine split-K partials (4 splits) -> ctx bf16.  1024 x 256.
// ---------------------------------------------------------------------------
__global__ __launch_bounds__(256) void combine_kernel(
    const u16* __restrict__ Opart, const float* __restrict__ Lpart,
    u16* __restrict__ ctx)
{
  int idx = blockIdx.x * 256 + threadIdx.x;
  int n = idx >> 6;
  int c8 = idx & 63;
  int h = c8 >> 3;
  int vd0 = (c8 & 7) * 8;

  float acc[8] = {0, 0, 0, 0, 0, 0, 0, 0};
  float lsum = 0.f;
#pragma unroll
  for (int s = 0; s < 4; ++s) {
    U128 u;
    u.u = *(const uint4*)(Opart + ((size_t)(s * NHEADS + h) * N_TOK + n) * 64 + vd0);
#pragma unroll
    for (int j = 0; j < 8; ++j) acc[j] += bf2f(u.s[j]);
    lsum += Lpart[((size_t)s * NHEADS + h) * N_TOK + n];
  }
  float inv = 1.f / lsum;
  U128 u;
#pragma unroll
  for (int j = 0; j < 8; ++j) u.s[j] = f2bf(acc[j] * inv);
  *(uint4*)(ctx + (size_t)n * DMODEL + h * HDIM + vd0) = u.u;
}

// ---------------------------------------------------------------------------
// Kernel 4: output projection + bias + residual, 64x64 tile, double-buffered.
// grid (64, 8) = 512 blocks = 2/CU (r8's 128-tile gave 256 blocks = 1/CU).
// ---------------------------------------------------------------------------
__global__ __launch_bounds__(256) void gemmo_kernel(
    const u16* __restrict__ ctx, const u16* __restrict__ WOb,
    const float* __restrict__ bO, const float* __restrict__ resid,
    float* __restrict__ Y)
{
  const int m0 = blockIdx.x * 64;
  const int j0 = blockIdx.y * 64;
  const int tid = threadIdx.x;
  const int w = tid >> 6, lane = tid & 63, quad = lane >> 4, l = lane & 15;

  __shared__ bf16x8 sA[2][8][64];  // 16 KB
  __shared__ bf16x8 sB[2][8][64];  // 16 KB

  const f32x4 zero = {0.f, 0.f, 0.f, 0.f};
  f32x4 acc[4];
#pragma unroll
  for (int s = 0; s < 4; ++s) acc[s] = zero;

  auto stage = [&](int kt, int buf) {
    const int k0 = kt * 64;
#pragma unroll
    for (int i = 0; i < 2; ++i) {
      const int chunk = 2 * w + i;
      const u16* ag = ctx + (size_t)(m0 + lane) * DMODEL + k0 + chunk * 8;
      ldg2lds16(ag, (char*)&sA[buf][chunk][0]);
      const u16* bg = WOb + (size_t)(j0 + lane) * DMODEL + k0 + chunk * 8;
      ldg2lds16(bg, (char*)&sB[buf][chunk][0]);
    }
  };

  stage(0, 0);
  __syncthreads();
  for (int kt = 0; kt < 8; ++kt) {
    const int buf = kt & 1;
    if (kt + 1 < 8) stage(kt + 1, buf ^ 1);
#pragma unroll
    for (int c = 0; c < 2; ++c) {
      bf16x8 af = sA[buf][c * 4 + quad][w * 16 + l];
#pragma unroll
      for (int s = 0; s < 4; ++s) {
        bf16x8 bfb = sB[buf][c * 4 + quad][s * 16 + l];
        acc[s] = __builtin_amdgcn_mfma_f32_16x16x32_bf16(af, bfb, acc[s], 0, 0, 0);
      }
    }
    __syncthreads();
  }
#pragma unroll
  for (int s = 0; s < 4; ++s) {
    int j = j0 + s * 16 + l;
    float bv = bO[j];
    int n0 = m0 + w * 16 + quad * 4;
#pragma unroll
    for (int r = 0; r < 4; ++r)
      Y[(size_t)(n0 + r) * DMODEL + j] = acc[s][r] + bv + resid[(size_t)(n0 + r) * DMODEL + j];
  }
}

// ---------------------------------------------------------------------------
// Kernel 5: LayerNorm, one wave per row
// ---------------------------------------------------------------------------
__global__ __launch_bounds__(256) void ln_kernel(
    const float* __restrict__ X, const float* __restrict__ gamma,
    const float* __restrict__ beta, float* __restrict__ Y)
{
  const int w = threadIdx.x >> 6, lane = threadIdx.x & 63;
  const int row = blockIdx.x * 4 + w;
  const float* x = X + (size_t)row * DMODEL + lane * 8;
  float4 a = *(const float4*)x;
  float4 b = *(const float4*)(x + 4);

  float s = a.x + a.y + a.z + a.w + b.x + b.y + b.z + b.w;
#pragma unroll
  for (int m = 1; m < 64; m <<= 1) s += __shfl_xor(s, m);
  float mu = s * (1.f / DMODEL);

  float d0 = a.x - mu, d1 = a.y - mu, d2 = a.z - mu, d3 = a.w - mu;
  float d4 = b.x - mu, d5 = b.y - mu, d6 = b.z - mu, d7 = b.w - mu;
  float v = d0*d0 + d1*d1 + d2*d2 + d3*d3 + d4*d4 + d5*d5 + d6*d6 + d7*d7;
#pragma unroll
  for (int m = 1; m < 64; m <<= 1) v += __shfl_xor(v, m);
  float sc = rsqrtf(v * (1.f / DMODEL) + 1e-5f);

  const float* g = gamma + lane * 8;
  const float* be = beta + lane * 8;
  float4 go = *(const float4*)g;
  float4 g1 = *(const float4*)(g + 4);
  float4 bo = *(const float4*)be;
  float4 b1 = *(const float4*)(be + 4);

  float4 y0, y1;
  y0.x = d0 * sc * go.x + bo.x;  y0.y = d1 * sc * go.y + bo.y;
  y0.z = d2 * sc * go.z + bo.z;  y0.w = d3 * sc * go.w + bo.w;
  y1.x = d4 * sc * g1.x + b1.x;  y1.y = d5 * sc * g1.y + b1.y;
  y1.z = d6 * sc * g1.z + b1.z;  y1.w = d7 * sc * g1.w + b1.w;

  float* yp = Y + (size_t)row * DMODEL + lane * 8;
  *(float4*)yp = y0;
  *(float4*)(yp + 4) = y1;
}

// ---------------------------------------------------------------------------
extern "C" void kernel_launch(void* const* d_in, const int* in_sizes, int n_in,
                              void* d_out, int out_size, void* d_ws, size_t ws_size,
                              hipStream_t stream)
{
  const float* Q     = (const float*)d_in[0];
  const float* K     = (const float*)d_in[1];
  const float* V     = (const float*)d_in[2];
  const float* WQ    = (const float*)d_in[3];
  const float* bQ    = (const float*)d_in[4];
  const float* WK    = (const float*)d_in[5];
  const float* bK    = (const float*)d_in[6];
  const float* WV    = (const float*)d_in[7];
  const float* bV    = (const float*)d_in[8];
  const float* WO    = (const float*)d_in[9];
  const float* bO    = (const float*)d_in[10];
  const float* gamma = (const float*)d_in[11];
  const float* beta  = (const float*)d_in[12];

  const size_t MB = 1ull << 20;
  char* ws = (char*)d_ws;
  u16* Qb   = (u16*)(ws + 0 * MB);                  // 4 MB each
  u16* Kb   = (u16*)(ws + 4 * MB);
  u16* Vb   = (u16*)(ws + 8 * MB);
  u16* WQb  = (u16*)(ws + 12 * MB);                 // 0.5 MB each
  u16* WKb  = (u16*)(ws + 12 * MB + 512 * 1024);
  u16* WVb  = (u16*)(ws + 13 * MB);
  u16* WOb  = (u16*)(ws + 13 * MB + 512 * 1024);
  u16* Qs   = (u16*)(ws + 14 * MB);                 // 4 MB each
  u16* Ks   = (u16*)(ws + 18 * MB);
  u16* Vt   = (u16*)(ws + 22 * MB);                 // projected V^T [j][n]
  u16* ctx  = (u16*)(ws + 26 * MB);
  u16* Opart = (u16*)(ws + 30 * MB);                // 16 MB bf16 (dead after combine)
  float* tmp = (float*)(ws + 30 * MB);              // 8 MB, overlays Opart
  float* Lpart = (float*)(ws + 46 * MB);            // 0.5 MB
  float* out = (float*)d_out;

  cvt7_kernel<<<7168, 256, 0, stream>>>(Q, K, V, WQ, WK, WV, WO,
                                        Qb, Kb, Vb, WQb, WKb, WVb, WOb);
  proj3_kernel<<<dim3(32, 8, 3), 256, 0, stream>>>(Qb, Kb, Vb, WQb, WKb, WVb,
                                                   bQ, bK, bV, Qs, Ks, Vt);
  attn_kernel<<<dim3(32, 16), 512, 0, stream>>>(Qs, Ks, Vt, Opart, Lpart);
  combine_kernel<<<1024, 256, 0, stream>>>(Opart, Lpart, ctx);
  gemmo_kernel<<<dim3(64, 8), 256, 0, stream>>>(ctx, WOb, bO, Q, tmp);
  ln_kernel<<<1024, 256, 0, stream>>>(tmp, gamma, beta, out);
}